// Round 13
// baseline (222.567 us; speedup 1.0000x reference)
//
#include <hip/hip_runtime.h>

// Problem constants (match reference)
#define BATCH 8192
#define TSTEPS 200
#define FEAT 16
#define HID 32
#define GATES 128   // 4*HID, Keras order: i | f | cc | o
#define DOUT 60
#define ROWS 16     // batch rows per block (one MFMA N-tile)
#define HSTRIDE 40  // LDS h row stride in halves (80 B)
#define NL2E -1.44269504088896340736f

typedef __fp16 half2v __attribute__((ext_vector_type(2)));
typedef __fp16 half4v __attribute__((ext_vector_type(4)));
typedef __fp16 half8v __attribute__((ext_vector_type(8)));
typedef float  float4v __attribute__((ext_vector_type(4)));

__device__ __forceinline__ half2v pkrtz(float a, float b) {
    return __builtin_amdgcn_cvt_pkrtz(a, b);
}

__device__ __forceinline__ half4v pack4(float4 v) {
    half2v lo = pkrtz(v.x, v.y);
    half2v hi = pkrtz(v.z, v.w);
    half4v r;
    r[0] = lo[0]; r[1] = lo[1]; r[2] = hi[0]; r[3] = hi[1];
    return r;
}

// Wave barrier WITHOUT the vmcnt drain (verified R11/R12). lgkmcnt(0)
// orders this wave's ds_write/ds_read around s_barrier; x prefetch (VMEM)
// stays in flight across it.
__device__ __forceinline__ void lds_barrier() {
    __builtin_amdgcn_sched_barrier(0);
    asm volatile("s_waitcnt lgkmcnt(0)\n\ts_barrier" ::: "memory");
    __builtin_amdgcn_sched_barrier(0);
}

// R13: EIGHT-wave gate-split -> 4096 waves = 4 waves/SIMD chip-wide.
// Wave w (0..7) owns h-units [4w, 4w+4) = 16 gate columns = ONE 16x16 MFMA
// tile, column-permuted: D row m -> gate (m&3), unit 4w + (m>>2), i.e.
// col(m) = 32*(m&3) + 4*w + (m>>2).
// Lane (g,n16) holds D rows m=4g+r -> gates r=i,f,cc,o for (unit 4w+g,
// batch row n16): the ENTIRE gate set of one output is lane-local in one
// accumulator. Epilogue: 3 exp2 + 1 rcp + ~12 VALU; h write = one
// ds_write_b16 at [row n16][unit 4w+g]. Next step's B-frag (units 8g..8g+7,
// row n16) = one ds_read_b128 (unchanged).
// 512 blocks x 8 waves = 2 blocks/CU = 16 waves/CU = 4/SIMD: per-wave issue
// (~140 cy) x 4 fills the ~550 cy recurrence chain R12 left half-naked.
// Fragment layouts (gfx950, verified R2/R4/R9):
//   16x16x32 A[m][k]: m=lane&15, k=(lane>>4)*8+j ; B[k][n]: n=lane&15, same k
//   16x16x16 A[m][k]: m=lane&15, k=(lane>>4)*4+j ; B[k][n]: n=lane&15, same k
//   D[m][n]: n=lane&15, m=(lane>>4)*4+r
// Epilogue math (R9 lineage, unpaired rcp -- bit-accurate or better):
//   gates i,f,o prescaled by -log2(e); num = c*d_i + relu(cc)*d_f;
//   ee = d_i*d_f*d_o; ie = rcp(ee); c' = num*(ie*d_o); h = relu(num)*ie.
template <bool DO_XW, bool DO_LOAD, int LOFF>
__device__ __forceinline__ void lstm_step(
    float4& XN, const float* xp,
    const half8v& aU, const half4v& aW, const float4v& bias,
    float4v& accx, float& cst,
    const __fp16* hr, __fp16* hw, int hroff, int hwoff)
{
    half8v hB = *reinterpret_cast<const half8v*>(&hr[hroff]);

    float4v acc = __builtin_amdgcn_mfma_f32_16x16x32_f16(
        aU, hB, accx, 0, 0, 0);

    if (DO_XW) {
        half4v ax = pack4(XN);
        accx = __builtin_amdgcn_mfma_f32_16x16x16f16(aW, ax, bias, 0, 0, 0);
    }
    if (DO_LOAD)
        XN = *reinterpret_cast<const float4*>(xp + LOFF);

    // acc = {i~, f~, cc, o~} for (unit 4w+g, row n16)
    float ei = __builtin_amdgcn_exp2f(acc[0]);
    float ef = __builtin_amdgcn_exp2f(acc[1]);
    float eo = __builtin_amdgcn_exp2f(acc[3]);
    float di  = 1.0f + ei;
    float df  = 1.0f + ef;
    float dov = 1.0f + eo;
    float rc  = fmaxf(acc[2], 0.0f);
    float num = fmaf(cst, di, rc * df);
    float ee  = (di * df) * dov;
    float ie  = __builtin_amdgcn_rcpf(ee);
    cst = num * (ie * dov);                      // c' = num/(di*df)
    float h = fmaxf(num, 0.0f) * ie;             // relu(c')*sig(o)
    hw[hwoff] = (__fp16)h;                       // 2B ds_write_b16

    lds_barrier();   // LDS-only sync: x loads stay in flight (no vmcnt drain)
}

__global__ __launch_bounds__(512, 1) void lstm_mfma(
    const float* __restrict__ x,    // [B, T, F]
    const float* __restrict__ W,    // [F, 128]
    const float* __restrict__ U,    // [H, 128]
    const float* __restrict__ bg,   // [128]
    const float* __restrict__ W1,   // [H, 60]
    const float* __restrict__ b1,   // [60]
    const float* __restrict__ W2,   // [H, 60]
    const float* __restrict__ b2,   // [60]
    float* __restrict__ out)        // [2 * B * 60] (long || lat)
{
    const int tid  = threadIdx.x;   // 512 threads = 8 waves
    const int lane = tid & 63;
    const int w    = tid >> 6;      // unit-quad: 0..7
    const int n16  = lane & 15;     // batch row within tile
    const int g    = lane >> 4;     // k-quad / D-row-quad
    const int b0   = blockIdx.x * ROWS;

    __shared__ __align__(16) __fp16 hbuf[2][ROWS * HSTRIDE];

    // ---- stationary A-frags: U^T (K=32), W^T (K=16), bias (per D-row) ----
    // A column for frag row n16: gate n16&3, unit 4w + (n16>>2).
    half8v  aU;
    half4v  aW;
    float4v bias;
    {
        const int gA   = n16 & 3;
        const float sA = (gA == 2) ? 1.0f : NL2E;
        const int colA = 32 * gA + 4 * w + (n16 >> 2);
        #pragma unroll
        for (int j = 0; j < 8; j++)
            aU[j] = (__fp16)(U[(8 * g + j) * GATES + colA] * sA);
        #pragma unroll
        for (int j = 0; j < 4; j++)
            aW[j] = (__fp16)(W[(4 * g + j) * GATES + colA] * sA);
        #pragma unroll
        for (int r = 0; r < 4; r++)   // D row m=4g+r -> gate r, unit 4w+g
            bias[r] = bg[32 * r + 4 * w + g] * ((r == 2) ? 1.0f : NL2E);
    }

    // zero h_0 buffer
    for (int i = tid; i < ROWS * HSTRIDE; i += 512) hbuf[0][i] = (__fp16)0.f;

    // x source: lane reads x[b0+n16][t][4g .. 4g+3] (8 waves duplicate;
    // same-block duplicates hit L1)
    const float* xrow = x + (size_t)(b0 + n16) * TSTEPS * FEAT + 4 * g;

    float4 xf0 = *reinterpret_cast<const float4*>(xrow + FEAT);        // x_1
    float4 xf1 = *reinterpret_cast<const float4*>(xrow + 2 * FEAT);    // x_2

    // accx(0) = bias + W^T·x_0^T
    float4v accx;
    {
        half4v a0 = pack4(*reinterpret_cast<const float4*>(xrow));
        accx = __builtin_amdgcn_mfma_f32_16x16x16f16(aW, a0, bias, 0, 0, 0);
    }

    float cst = 0.f;
    const int hroff = n16 * HSTRIDE + 8 * g;       // B-frag read (16B)
    const int hwoff = n16 * HSTRIDE + 4 * w + g;   // h write (2B)

    __syncthreads();   // h_0 zero-init visible (once; drain cost negligible)

    // Branch-free main loop: steps 0..195. Step t reads hbuf[t&1], writes
    // hbuf[(t+1)&1]. Invariant: xf0 = x_{t+1}, xf1 = x_{t+2}, xp = &x_t.
    // Loads cross barriers un-drained; use-site vmcnt waits land 2 full
    // steps after issue.
    const float* xp = xrow;
    for (int it = 0; it < (TSTEPS - 4) / 2; ++it) {
        lstm_step<true, true, 3 * FEAT>(xf0, xp, aU, aW, bias, accx, cst,
                                        hbuf[0], hbuf[1], hroff, hwoff);
        lstm_step<true, true, 4 * FEAT>(xf1, xp, aU, aW, bias, accx, cst,
                                        hbuf[1], hbuf[0], hroff, hwoff);
        xp += 2 * FEAT;
    }
    // Peeled tail: steps 196..199 (xp == &x_196; xf0=x_197, xf1=x_198)
    lstm_step<true, true, 3 * FEAT>(xf0, xp, aU, aW, bias, accx, cst,
                                    hbuf[0], hbuf[1], hroff, hwoff);  // 196
    lstm_step<true, false, 0>(xf1, xp, aU, aW, bias, accx, cst,
                              hbuf[1], hbuf[0], hroff, hwoff);        // 197
    lstm_step<true, false, 0>(xf0, xp, aU, aW, bias, accx, cst,
                              hbuf[0], hbuf[1], hroff, hwoff);        // 198
    lstm_step<false, false, 0>(xf1, xp, aU, aW, bias, accx, cst,
                               hbuf[1], hbuf[0], hroff, hwoff);       // 199

    // h_T = h_200 lives in hbuf[0]; step 199's lds_barrier covers the reads.
    // ---- heads: out = h_T @ W1/W2 + b (fp32, h from LDS, 512 threads) ----
    const __fp16* hf = &hbuf[0][0];
    for (int idx = tid; idx < ROWS * DOUT; idx += 512) {
        const int row = idx / DOUT;
        const int d   = idx - row * DOUT;
        float s1 = b1[d], s2 = b2[d];
        #pragma unroll 8
        for (int k = 0; k < HID; k++) {
            float hv = (float)hf[row * HSTRIDE + k];
            s1 = fmaf(hv, W1[k * DOUT + d], s1);
            s2 = fmaf(hv, W2[k * DOUT + d], s2);
        }
        out[(size_t)(b0 + row) * DOUT + d] = s1;
        out[(size_t)BATCH * DOUT + (size_t)(b0 + row) * DOUT + d] = s2;
    }
}

extern "C" void kernel_launch(void* const* d_in, const int* in_sizes, int n_in,
                              void* d_out, int out_size, void* d_ws, size_t ws_size,
                              hipStream_t stream) {
    const float* x  = (const float*)d_in[0];
    const float* W  = (const float*)d_in[1];
    const float* U  = (const float*)d_in[2];
    const float* bg = (const float*)d_in[3];
    const float* W1 = (const float*)d_in[4];
    const float* b1 = (const float*)d_in[5];
    const float* W2 = (const float*)d_in[6];
    const float* b2 = (const float*)d_in[7];
    float* out = (float*)d_out;

    dim3 grid(BATCH / ROWS);   // 512 blocks x 8 waves = 4096 waves (4/SIMD)
    dim3 block(512);
    lstm_mfma<<<grid, block, 0, stream>>>(x, W, U, bg, W1, b1, W2, b2, out);
}